// Round 4
// baseline (82.056 us; speedup 1.0000x reference)
//
#include <hip/hip_runtime.h>

// CompositionalEmbeddings: out[b,s, 0:512]   = token_table[id]
//                          out[b,s, 512:1024] = cat_table[id]
// cat_table = concat(op[10], var[10], const[10], struct[10], special[49960]);
// category start offsets align with id ranges -> direct gather.
//
// Memory-bound double-gather. Round 4: 4 tokens per block for MLP —
// each thread preloads 4 ids, issues 4 independent float4 gathers, then
// 4 nontemporal stores. Lanes 0-127 = token half, 128-255 = category half
// (wave-uniform). NT stores keep the ~205 MB of tables L3-resident.

typedef float f32x4 __attribute__((ext_vector_type(4)));

#define V4_PER_HALF 128   // 512 floats / 4
#define TPB 4             // tokens per block

__global__ __launch_bounds__(256) void compemb_kernel(
    const int* __restrict__ ids,
    const f32x4* __restrict__ tok,     // [50000][128]
    const f32x4* __restrict__ op_t,    // [10][128]
    const f32x4* __restrict__ var_t,   // [10][128]
    const f32x4* __restrict__ cst_t,   // [10][128]
    const f32x4* __restrict__ str_t,   // [10][128]
    const f32x4* __restrict__ spc_t,   // [49960][128]
    f32x4* __restrict__ out,           // [n_tokens][256]
    int n_tokens)
{
    const long long base = (long long)blockIdx.x * TPB;
    const int t = threadIdx.x;
    const int e = t & (V4_PER_HALF - 1);

    int id[TPB];
#pragma unroll
    for (int k = 0; k < TPB; ++k)
        id[k] = ids[base + k];          // block-uniform scalar loads

    f32x4 v[TPB];
#pragma unroll
    for (int k = 0; k < TPB; ++k) {
        const f32x4* src;
        long long row;
        if (t < V4_PER_HALF) {
            src = tok;  row = id[k];
        } else {
            const int c = id[k];
            if (c < 10)      { src = op_t;  row = c; }
            else if (c < 20) { src = var_t; row = c - 10; }
            else if (c < 30) { src = cst_t; row = c - 20; }
            else if (c < 40) { src = str_t; row = c - 30; }
            else             { src = spc_t; row = c - 40; }
        }
        v[k] = src[row * V4_PER_HALF + e];   // 4 independent gathers in flight
    }

#pragma unroll
    for (int k = 0; k < TPB; ++k)
        __builtin_nontemporal_store(v[k], &out[(base + k) * 256 + t]);
}

extern "C" void kernel_launch(void* const* d_in, const int* in_sizes, int n_in,
                              void* d_out, int out_size, void* d_ws, size_t ws_size,
                              hipStream_t stream) {
    const int*   ids   = (const int*)  d_in[0];
    const f32x4* tok   = (const f32x4*)d_in[1];
    const f32x4* op_t  = (const f32x4*)d_in[2];
    const f32x4* var_t = (const f32x4*)d_in[3];
    const f32x4* cst_t = (const f32x4*)d_in[4];
    const f32x4* str_t = (const f32x4*)d_in[5];
    const f32x4* spc_t = (const f32x4*)d_in[6];
    f32x4* out = (f32x4*)d_out;

    const int n_tokens = in_sizes[0];          // 65536, divisible by TPB
    compemb_kernel<<<n_tokens / TPB, 256, 0, stream>>>(
        ids, tok, op_t, var_t, cst_t, str_t, spc_t, out, n_tokens);
}